// Round 1
// baseline (4799.976 us; speedup 1.0000x reference)
//
#include <hip/hip_runtime.h>
#include <hip/hip_bf16.h>
#include <math.h>

constexpr int N_NODES = 200000;
constexpr int E_EDGES = 3200000;
constexpr int F_IN    = 128;
constexpr int D       = 64;
constexpr int G_GRAPHS = 512;
constexpr int T_OUT   = 10;

// ---------------------------------------------------------------- degree
__global__ __launch_bounds__(256) void deg_kernel(const int* __restrict__ dst,
                                                  int* __restrict__ deg) {
    int e = blockIdx.x * 256 + threadIdx.x;
    if (e < E_EDGES) atomicAdd(&deg[dst[e]], 1);
}

__global__ __launch_bounds__(256) void dis_kernel(const int* __restrict__ deg,
                                                  float* __restrict__ dis) {
    int i = blockIdx.x * 256 + threadIdx.x;
    if (i < N_NODES) dis[i] = 1.0f / sqrtf((float)deg[i] + 1.0f);
}

// single-block exclusive scan of deg -> row_ptr (N+1)
__global__ __launch_bounds__(1024) void scan_kernel(const int* __restrict__ deg,
                                                    int* __restrict__ row_ptr) {
    __shared__ int part[1024];
    const int t = threadIdx.x;
    const int chunk = (N_NODES + 1023) / 1024;
    int beg = t * chunk;
    int end = beg + chunk; if (end > N_NODES) end = N_NODES;
    int s = 0;
    for (int i = beg; i < end; ++i) s += deg[i];
    part[t] = s;
    __syncthreads();
    for (int off = 1; off < 1024; off <<= 1) {
        int v = (t >= off) ? part[t - off] : 0;
        __syncthreads();
        part[t] += v;
        __syncthreads();
    }
    int excl = (t == 0) ? 0 : part[t - 1];
    for (int i = beg; i < end; ++i) { row_ptr[i] = excl; excl += deg[i]; }
    if (t == 1023) row_ptr[N_NODES] = part[1023];   // == E
}

__global__ __launch_bounds__(256) void place_kernel(const int* __restrict__ src,
                                                    const int* __restrict__ dst,
                                                    const float* __restrict__ dis,
                                                    const int* __restrict__ row_ptr,
                                                    int* __restrict__ cursor,
                                                    int* __restrict__ csr_src,
                                                    float* __restrict__ csr_coef) {
    int e = blockIdx.x * 256 + threadIdx.x;
    if (e < E_EDGES) {
        int s = src[e], d = dst[e];
        int pos = row_ptr[d] + atomicAdd(&cursor[d], 1);
        csr_src[pos]  = s;
        csr_coef[pos] = dis[s] * dis[d];
    }
}

// ---------------------------------------------------------------- GEMM
// out[r][c] = sum_k in[r][k] * W[c][k];  64 rows x 64 cols per block, 256 thr.
// LDS XOR-swizzle: float4-granule g stored at g ^ ((row>>2)&7) so the
// 16-distinct-row ds_read_b128 in the inner loop is <=2-way (free, m136).
template<int K, bool FUSED_MAX>
__global__ __launch_bounds__(256) void gemm_k(const float* __restrict__ in,
                                              const float* __restrict__ W,
                                              float* __restrict__ out,
                                              const float* __restrict__ bias,
                                              const int* __restrict__ batch,
                                              int* __restrict__ pooled,
                                              int layer) {
    constexpr int GPR = K / 4;           // float4 granules per row
    __shared__ float Xs[64 * K];
    __shared__ float Ws[D * K];
    const int tid = threadIdx.x;
    const size_t row0 = (size_t)blockIdx.x * 64;

    for (int li = tid; li < 64 * GPR; li += 256) {
        int r = li / GPR, g = li % GPR;
        float4 v = *(const float4*)(in + (row0 + r) * K + g * 4);
        int gs = g ^ ((r >> 2) & 7);
        *(float4*)(Xs + r * K + gs * 4) = v;
    }
    for (int li = tid; li < D * GPR; li += 256) {
        int r = li / GPR, g = li % GPR;
        float4 v = *(const float4*)(W + r * K + g * 4);
        int gs = g ^ ((r >> 2) & 7);
        *(float4*)(Ws + r * K + gs * 4) = v;
    }
    __syncthreads();

    const int lane = tid & 63;
    const int wave = tid >> 6;
    const int rg = lane & 15;            // 16 row groups
    const int cg = wave * 4 + (lane >> 4); // 16 col groups
    float acc[4][4] = {};
    #pragma unroll 8
    for (int kq = 0; kq < GPR; ++kq) {
        float4 xv[4], wv[4];
        #pragma unroll
        for (int i = 0; i < 4; ++i)
            xv[i] = *(const float4*)(Xs + (rg * 4 + i) * K + ((kq ^ (rg & 7)) * 4));
        #pragma unroll
        for (int j = 0; j < 4; ++j)
            wv[j] = *(const float4*)(Ws + (cg * 4 + j) * K + ((kq ^ (cg & 7)) * 4));
        #pragma unroll
        for (int i = 0; i < 4; ++i)
            #pragma unroll
            for (int j = 0; j < 4; ++j)
                acc[i][j] += xv[i].x * wv[j].x + xv[i].y * wv[j].y +
                             xv[i].z * wv[j].z + xv[i].w * wv[j].w;
    }

    #pragma unroll
    for (int i = 0; i < 4; ++i) {
        size_t r = row0 + rg * 4 + i;
        if constexpr (FUSED_MAX) {
            int bg = batch[r];
            int pbase = bg * (4 * D) + layer * D;
            float4 o;
            float* op = (float*)&o;
            #pragma unroll
            for (int j = 0; j < 4; ++j) {
                int c = cg * 4 + j;
                float v = fmaxf(acc[i][j] + bias[c], 0.0f);
                op[j] = v;
                atomicMax(&pooled[pbase + c], __float_as_int(v));
            }
            *(float4*)(out + r * D + cg * 4) = o;
        } else {
            float4 o = make_float4(acc[i][0], acc[i][1], acc[i][2], acc[i][3]);
            *(float4*)(out + r * D + cg * 4) = o;
        }
    }
}

// ---------------------------------------------------------------- aggregate
// one wave per node, lane = feature. acc = self-loop + bias + sum_{edges}.
__global__ __launch_bounds__(256) void agg_kernel(const int* __restrict__ row_ptr,
                                                  const int* __restrict__ csr_src,
                                                  const float* __restrict__ csr_coef,
                                                  const float* __restrict__ Lbuf,
                                                  const float* __restrict__ dis,
                                                  const float* __restrict__ bias,
                                                  float* __restrict__ A) {
    int v = __builtin_amdgcn_readfirstlane((int)(blockIdx.x * 4) + (int)(threadIdx.x >> 6));
    if (v >= N_NODES) return;
    const int lane = threadIdx.x & 63;
    const int beg = row_ptr[v];
    const int end = row_ptr[v + 1];
    float dd = dis[v];
    float acc = Lbuf[(size_t)v * D + lane] * (dd * dd) + bias[lane];
    #pragma unroll 4
    for (int p = beg; p < end; ++p) {
        int s = csr_src[p];
        float c = csr_coef[p];
        acc += Lbuf[(size_t)s * D + lane] * c;
    }
    A[(size_t)v * D + lane] = acc;
}

// ---------------------------------------------------------------- final MLP
__global__ __launch_bounds__(64) void mlp_kernel(const float* __restrict__ pooled,
                                                 const float* __restrict__ W1,
                                                 const float* __restrict__ b1,
                                                 const float* __restrict__ W2,
                                                 const float* __restrict__ b2,
                                                 float* __restrict__ out) {
    __shared__ float ps[4 * D];
    __shared__ float hs[D];
    const int g = blockIdx.x, t = threadIdx.x;
    *(float4*)(ps + t * 4) = *(const float4*)(pooled + (size_t)g * (4 * D) + t * 4);
    __syncthreads();
    float acc = b1[t];
    const float* w = W1 + (size_t)t * (4 * D);
    #pragma unroll 4
    for (int k = 0; k < 4 * D; k += 4) {
        float4 wv = *(const float4*)(w + k);
        float4 pv = *(const float4*)(ps + k);
        acc += wv.x * pv.x + wv.y * pv.y + wv.z * pv.z + wv.w * pv.w;
    }
    hs[t] = fmaxf(acc, 0.0f);
    __syncthreads();
    if (t < T_OUT) {
        float o = b2[t];
        const float* w2 = W2 + t * D;
        #pragma unroll
        for (int k = 0; k < D; ++k) o += hs[k] * w2[k];
        out[(size_t)g * T_OUT + t] = o;
    }
}

// ---------------------------------------------------------------- launch
extern "C" void kernel_launch(void* const* d_in, const int* in_sizes, int n_in,
                              void* d_out, int out_size, void* d_ws, size_t ws_size,
                              hipStream_t stream) {
    (void)in_sizes; (void)n_in; (void)out_size; (void)ws_size;
    const float* x     = (const float*)d_in[0];
    const int*   ei    = (const int*)d_in[1];
    const int*   batch = (const int*)d_in[2];
    const float* Wc[4] = {(const float*)d_in[4], (const float*)d_in[6],
                          (const float*)d_in[8], (const float*)d_in[10]};
    const float* bc[4] = {(const float*)d_in[5], (const float*)d_in[7],
                          (const float*)d_in[9], (const float*)d_in[11]};
    const float* Wmax = (const float*)d_in[12];
    const float* bmax = (const float*)d_in[13];
    const float* W1   = (const float*)d_in[14];
    const float* b1   = (const float*)d_in[15];
    const float* W2   = (const float*)d_in[16];
    const float* b2   = (const float*)d_in[17];
    float* out = (float*)d_out;

    float* fws = (float*)d_ws;
    size_t off = 0;
    float* L        = fws + off; off += (size_t)N_NODES * D;   // 51.2 MB (ping-pong)
    float* A        = fws + off; off += (size_t)N_NODES * D;   // 51.2 MB
    int*   csr_src  = (int*)(fws + off); off += E_EDGES;       // 12.8 MB
    float* csr_coef = fws + off; off += E_EDGES;               // 12.8 MB
    int*   row_ptr  = (int*)(fws + off); off += N_NODES + 16;
    int*   deg      = (int*)(fws + off); off += N_NODES;
    int*   cursor   = (int*)(fws + off); off += N_NODES;
    float* dis      = fws + off; off += N_NODES;
    int*   pooled   = (int*)(fws + off); off += G_GRAPHS * 4 * D;

    const int* srcI = ei;
    const int* dstI = ei + E_EDGES;

    hipMemsetAsync(deg,    0, sizeof(int) * N_NODES, stream);
    hipMemsetAsync(cursor, 0, sizeof(int) * N_NODES, stream);
    hipMemsetAsync(pooled, 0, sizeof(int) * G_GRAPHS * 4 * D, stream);

    deg_kernel <<<(E_EDGES + 255) / 256, 256, 0, stream>>>(dstI, deg);
    dis_kernel <<<(N_NODES + 255) / 256, 256, 0, stream>>>(deg, dis);
    scan_kernel<<<1, 1024, 0, stream>>>(deg, row_ptr);
    place_kernel<<<(E_EDGES + 255) / 256, 256, 0, stream>>>(srcI, dstI, dis, row_ptr,
                                                            cursor, csr_src, csr_coef);

    const float* cur = x;
    for (int l = 0; l < 4; ++l) {
        if (l == 0)
            gemm_k<F_IN, false><<<N_NODES / 64, 256, 0, stream>>>(cur, Wc[0], L,
                                                                  nullptr, nullptr, nullptr, 0);
        else
            gemm_k<D, false><<<N_NODES / 64, 256, 0, stream>>>(cur, Wc[l], L,
                                                               nullptr, nullptr, nullptr, 0);
        agg_kernel<<<N_NODES / 4, 256, 0, stream>>>(row_ptr, csr_src, csr_coef,
                                                    L, dis, bc[l], A);
        gemm_k<D, true><<<N_NODES / 64, 256, 0, stream>>>(A, Wmax, L,
                                                          bmax, batch, pooled, l);
        cur = L;
    }
    mlp_kernel<<<G_GRAPHS, 64, 0, stream>>>((const float*)pooled, W1, b1, W2, b2, out);
}

// Round 2
// 1751.968 us; speedup vs baseline: 2.7398x; 2.7398x over previous
//
#include <hip/hip_runtime.h>
#include <hip/hip_bf16.h>
#include <math.h>

constexpr int N_NODES = 200000;
constexpr int E_EDGES = 3200000;
constexpr int F_IN    = 128;
constexpr int D       = 64;
constexpr int G_GRAPHS = 512;
constexpr int T_OUT   = 10;

// ---------------------------------------------------------------- degree
__global__ __launch_bounds__(256) void deg_kernel(const int* __restrict__ dst,
                                                  int* __restrict__ deg) {
    int e = blockIdx.x * 256 + threadIdx.x;
    if (e < E_EDGES) atomicAdd(&deg[dst[e]], 1);
}

__global__ __launch_bounds__(256) void dis_kernel(const int* __restrict__ deg,
                                                  float* __restrict__ dis) {
    int i = blockIdx.x * 256 + threadIdx.x;
    if (i < N_NODES) dis[i] = 1.0f / sqrtf((float)deg[i] + 1.0f);
}

// single-block exclusive scan of deg -> row_ptr (N+1)
__global__ __launch_bounds__(1024) void scan_kernel(const int* __restrict__ deg,
                                                    int* __restrict__ row_ptr) {
    __shared__ int part[1024];
    const int t = threadIdx.x;
    const int chunk = (N_NODES + 1023) / 1024;
    int beg = t * chunk;
    int end = beg + chunk; if (end > N_NODES) end = N_NODES;
    int s = 0;
    for (int i = beg; i < end; ++i) s += deg[i];
    part[t] = s;
    __syncthreads();
    for (int off = 1; off < 1024; off <<= 1) {
        int v = (t >= off) ? part[t - off] : 0;
        __syncthreads();
        part[t] += v;
        __syncthreads();
    }
    int excl = (t == 0) ? 0 : part[t - 1];
    for (int i = beg; i < end; ++i) { row_ptr[i] = excl; excl += deg[i]; }
    if (t == 1023) row_ptr[N_NODES] = part[1023];   // == E
}

__global__ __launch_bounds__(256) void place_kernel(const int* __restrict__ src,
                                                    const int* __restrict__ dst,
                                                    const float* __restrict__ dis,
                                                    const int* __restrict__ row_ptr,
                                                    int* __restrict__ cursor,
                                                    int* __restrict__ csr_src,
                                                    float* __restrict__ csr_coef) {
    int e = blockIdx.x * 256 + threadIdx.x;
    if (e < E_EDGES) {
        int s = src[e], d = dst[e];
        int pos = row_ptr[d] + atomicAdd(&cursor[d], 1);
        csr_src[pos]  = s;
        csr_coef[pos] = dis[s] * dis[d];
    }
}

// ---------------------------------------------------------------- GEMM
// out[r][c] = sum_k in[r][k] * W[c][k];  64 rows x 64 cols per block, 256 thr.
// LDS XOR-swizzle on float4 granules so inner-loop ds_read_b128 is <=2-way.
// FUSED_MAX: stage relu tile in LDS, segmented max over sorted batch ->
// ~2 atomics per (graph,col) per block instead of per-element atomics.
template<int K, bool FUSED_MAX>
__global__ __launch_bounds__(256) void gemm_k(const float* __restrict__ in,
                                              const float* __restrict__ W,
                                              float* __restrict__ out,
                                              const float* __restrict__ bias,
                                              const int* __restrict__ batch,
                                              int* __restrict__ pooled,
                                              int layer) {
    constexpr int GPR = K / 4;           // float4 granules per row
    __shared__ float smem[64 * K + D * K];
    __shared__ int   bs[64];
    float* Xs = smem;
    float* Ws = smem + 64 * K;
    const int tid = threadIdx.x;
    const size_t row0 = (size_t)blockIdx.x * 64;

    for (int li = tid; li < 64 * GPR; li += 256) {
        int r = li / GPR, g = li % GPR;
        float4 v = *(const float4*)(in + (row0 + r) * K + g * 4);
        int gs = g ^ ((r >> 2) & 7);
        *(float4*)(Xs + r * K + gs * 4) = v;
    }
    for (int li = tid; li < D * GPR; li += 256) {
        int r = li / GPR, g = li % GPR;
        float4 v = *(const float4*)(W + r * K + g * 4);
        int gs = g ^ ((r >> 2) & 7);
        *(float4*)(Ws + r * K + gs * 4) = v;
    }
    if (FUSED_MAX && tid < 64) bs[tid] = batch[row0 + tid];
    __syncthreads();

    const int lane = tid & 63;
    const int wave = tid >> 6;
    const int rg = lane & 15;              // 16 row groups
    const int cg = wave * 4 + (lane >> 4); // 16 col groups
    float acc[4][4] = {};
    #pragma unroll 8
    for (int kq = 0; kq < GPR; ++kq) {
        float4 xv[4], wv[4];
        #pragma unroll
        for (int i = 0; i < 4; ++i)
            xv[i] = *(const float4*)(Xs + (rg * 4 + i) * K + ((kq ^ (rg & 7)) * 4));
        #pragma unroll
        for (int j = 0; j < 4; ++j)
            wv[j] = *(const float4*)(Ws + (cg * 4 + j) * K + ((kq ^ (cg & 7)) * 4));
        #pragma unroll
        for (int i = 0; i < 4; ++i)
            #pragma unroll
            for (int j = 0; j < 4; ++j)
                acc[i][j] += xv[i].x * wv[j].x + xv[i].y * wv[j].y +
                             xv[i].z * wv[j].z + xv[i].w * wv[j].w;
    }

    if constexpr (FUSED_MAX) {
        // relu + write out + stage tile into LDS (reuse smem; 64x68 padded)
        __syncthreads();                    // done reading Xs/Ws
        float* Ts = smem;                   // 64*68 = 4352 floats <= 64*K+D*K (K=64)
        #pragma unroll
        for (int i = 0; i < 4; ++i) {
            size_t r = row0 + rg * 4 + i;
            float4 o;
            float* op = (float*)&o;
            #pragma unroll
            for (int j = 0; j < 4; ++j)
                op[j] = fmaxf(acc[i][j] + bias[cg * 4 + j], 0.0f);
            *(float4*)(out + r * D + cg * 4) = o;
            *(float4*)(Ts + (rg * 4 + i) * 68 + cg * 4) = o;
        }
        __syncthreads();
        if (tid < 64) {
            const int col = tid;
            float m = Ts[col];
            int bg = bs[0];
            #pragma unroll 8
            for (int r = 1; r < 64; ++r) {
                int b2 = bs[r];            // wave-uniform across cols
                float v = Ts[r * 68 + col];
                if (b2 != bg) {            // uniform branch
                    atomicMax(&pooled[bg * (4 * D) + layer * D + col], __float_as_int(m));
                    bg = b2; m = v;
                } else {
                    m = fmaxf(m, v);
                }
            }
            atomicMax(&pooled[bg * (4 * D) + layer * D + col], __float_as_int(m));
        }
    } else {
        #pragma unroll
        for (int i = 0; i < 4; ++i) {
            size_t r = row0 + rg * 4 + i;
            float4 o = make_float4(acc[i][0], acc[i][1], acc[i][2], acc[i][3]);
            *(float4*)(out + r * D + cg * 4) = o;
        }
    }
}

// ---------------------------------------------------------------- aggregate
// one wave per node, lane = feature. acc = self-loop + bias + sum_{edges}.
__global__ __launch_bounds__(256) void agg_kernel(const int* __restrict__ row_ptr,
                                                  const int* __restrict__ csr_src,
                                                  const float* __restrict__ csr_coef,
                                                  const float* __restrict__ Lbuf,
                                                  const float* __restrict__ dis,
                                                  const float* __restrict__ bias,
                                                  float* __restrict__ A) {
    int v = __builtin_amdgcn_readfirstlane((int)(blockIdx.x * 4) + (int)(threadIdx.x >> 6));
    if (v >= N_NODES) return;
    const int lane = threadIdx.x & 63;
    const int beg = row_ptr[v];
    const int end = row_ptr[v + 1];
    float dd = dis[v];
    float acc = Lbuf[(size_t)v * D + lane] * (dd * dd) + bias[lane];
    #pragma unroll 4
    for (int p = beg; p < end; ++p) {
        int s = csr_src[p];
        float c = csr_coef[p];
        acc += Lbuf[(size_t)s * D + lane] * c;
    }
    A[(size_t)v * D + lane] = acc;
}

// ---------------------------------------------------------------- final MLP
__global__ __launch_bounds__(64) void mlp_kernel(const float* __restrict__ pooled,
                                                 const float* __restrict__ W1,
                                                 const float* __restrict__ b1,
                                                 const float* __restrict__ W2,
                                                 const float* __restrict__ b2,
                                                 float* __restrict__ out) {
    __shared__ float ps[4 * D];
    __shared__ float hs[D];
    const int g = blockIdx.x, t = threadIdx.x;
    *(float4*)(ps + t * 4) = *(const float4*)(pooled + (size_t)g * (4 * D) + t * 4);
    __syncthreads();
    float acc = b1[t];
    const float* w = W1 + (size_t)t * (4 * D);
    #pragma unroll 4
    for (int k = 0; k < 4 * D; k += 4) {
        float4 wv = *(const float4*)(w + k);
        float4 pv = *(const float4*)(ps + k);
        acc += wv.x * pv.x + wv.y * pv.y + wv.z * pv.z + wv.w * pv.w;
    }
    hs[t] = fmaxf(acc, 0.0f);
    __syncthreads();
    if (t < T_OUT) {
        float o = b2[t];
        const float* w2 = W2 + t * D;
        #pragma unroll
        for (int k = 0; k < D; ++k) o += hs[k] * w2[k];
        out[(size_t)g * T_OUT + t] = o;
    }
}

// ---------------------------------------------------------------- launch
extern "C" void kernel_launch(void* const* d_in, const int* in_sizes, int n_in,
                              void* d_out, int out_size, void* d_ws, size_t ws_size,
                              hipStream_t stream) {
    (void)in_sizes; (void)n_in; (void)out_size; (void)ws_size;
    const float* x     = (const float*)d_in[0];
    const int*   ei    = (const int*)d_in[1];
    const int*   batch = (const int*)d_in[2];
    const float* Wc[4] = {(const float*)d_in[4], (const float*)d_in[6],
                          (const float*)d_in[8], (const float*)d_in[10]};
    const float* bc[4] = {(const float*)d_in[5], (const float*)d_in[7],
                          (const float*)d_in[9], (const float*)d_in[11]};
    const float* Wmax = (const float*)d_in[12];
    const float* bmax = (const float*)d_in[13];
    const float* W1   = (const float*)d_in[14];
    const float* b1   = (const float*)d_in[15];
    const float* W2   = (const float*)d_in[16];
    const float* b2   = (const float*)d_in[17];
    float* out = (float*)d_out;

    float* fws = (float*)d_ws;
    size_t off = 0;
    float* L        = fws + off; off += (size_t)N_NODES * D;   // 51.2 MB (ping-pong)
    float* A        = fws + off; off += (size_t)N_NODES * D;   // 51.2 MB
    int*   csr_src  = (int*)(fws + off); off += E_EDGES;       // 12.8 MB
    float* csr_coef = fws + off; off += E_EDGES;               // 12.8 MB
    int*   row_ptr  = (int*)(fws + off); off += N_NODES + 16;
    int*   deg      = (int*)(fws + off); off += N_NODES;
    int*   cursor   = (int*)(fws + off); off += N_NODES;
    float* dis      = fws + off; off += N_NODES;
    int*   pooled   = (int*)(fws + off); off += G_GRAPHS * 4 * D;

    const int* srcI = ei;
    const int* dstI = ei + E_EDGES;

    hipMemsetAsync(deg,    0, sizeof(int) * N_NODES, stream);
    hipMemsetAsync(cursor, 0, sizeof(int) * N_NODES, stream);
    hipMemsetAsync(pooled, 0, sizeof(int) * G_GRAPHS * 4 * D, stream);

    deg_kernel <<<(E_EDGES + 255) / 256, 256, 0, stream>>>(dstI, deg);
    dis_kernel <<<(N_NODES + 255) / 256, 256, 0, stream>>>(deg, dis);
    scan_kernel<<<1, 1024, 0, stream>>>(deg, row_ptr);
    place_kernel<<<(E_EDGES + 255) / 256, 256, 0, stream>>>(srcI, dstI, dis, row_ptr,
                                                            cursor, csr_src, csr_coef);

    const float* cur = x;
    for (int l = 0; l < 4; ++l) {
        if (l == 0)
            gemm_k<F_IN, false><<<N_NODES / 64, 256, 0, stream>>>(cur, Wc[0], L,
                                                                  nullptr, nullptr, nullptr, 0);
        else
            gemm_k<D, false><<<N_NODES / 64, 256, 0, stream>>>(cur, Wc[l], L,
                                                               nullptr, nullptr, nullptr, 0);
        agg_kernel<<<N_NODES / 4, 256, 0, stream>>>(row_ptr, csr_src, csr_coef,
                                                    L, dis, bc[l], A);
        gemm_k<D, true><<<N_NODES / 64, 256, 0, stream>>>(A, Wmax, L,
                                                          bmax, batch, pooled, l);
        cur = L;
    }
    mlp_kernel<<<G_GRAPHS, 64, 0, stream>>>((const float*)pooled, W1, b1, W2, b2, out);
}

// Round 3
// 1455.792 us; speedup vs baseline: 3.2972x; 1.2034x over previous
//
#include <hip/hip_runtime.h>
#include <hip/hip_bf16.h>
#include <math.h>

constexpr int N_NODES = 200000;
constexpr int E_EDGES = 3200000;
constexpr int F_IN    = 128;
constexpr int D       = 64;
constexpr int G_GRAPHS = 512;
constexpr int T_OUT   = 10;

constexpr int SCAN_CHUNK   = 2048;                                   // per block
constexpr int SCAN_NBLOCKS = (N_NODES + SCAN_CHUNK - 1) / SCAN_CHUNK; // 98

// ---------------------------------------------------------------- degree
__global__ __launch_bounds__(256) void deg_kernel(const int* __restrict__ dst,
                                                  int* __restrict__ deg) {
    int e = blockIdx.x * 256 + threadIdx.x;
    if (e < E_EDGES) atomicAdd(&deg[dst[e]], 1);
}

__global__ __launch_bounds__(256) void dis_kernel(const int* __restrict__ deg,
                                                  float* __restrict__ dis) {
    int i = blockIdx.x * 256 + threadIdx.x;
    if (i < N_NODES) dis[i] = 1.0f / sqrtf((float)deg[i] + 1.0f);
}

// ----------------------------------------------------- 3-phase parallel scan
__global__ __launch_bounds__(256) void scan_p1(const int* __restrict__ deg,
                                               int* __restrict__ bsum) {
    const int b = blockIdx.x, t = threadIdx.x;
    int idx0 = b * SCAN_CHUNK + t * 8;
    int s = 0;
    #pragma unroll
    for (int i = 0; i < 8; ++i) {
        int idx = idx0 + i;
        if (idx < N_NODES) s += deg[idx];
    }
    #pragma unroll
    for (int off = 32; off; off >>= 1) s += __shfl_down(s, off, 64);
    __shared__ int ws[4];
    if ((t & 63) == 0) ws[t >> 6] = s;
    __syncthreads();
    if (t == 0) bsum[b] = ws[0] + ws[1] + ws[2] + ws[3];
}

__global__ __launch_bounds__(128) void scan_p2(int* __restrict__ bsum,
                                               int* __restrict__ row_ptr) {
    __shared__ int tmp[128];
    const int t = threadIdx.x;
    int v = (t < SCAN_NBLOCKS) ? bsum[t] : 0;
    tmp[t] = v;
    __syncthreads();
    #pragma unroll
    for (int off = 1; off < 128; off <<= 1) {
        int u = (t >= off) ? tmp[t - off] : 0;
        __syncthreads();
        tmp[t] += u;
        __syncthreads();
    }
    if (t < SCAN_NBLOCKS) bsum[t] = tmp[t] - v;   // exclusive
    if (t == 0) row_ptr[N_NODES] = E_EDGES;
}

__global__ __launch_bounds__(256) void scan_p3(const int* __restrict__ deg,
                                               const int* __restrict__ bsum,
                                               int* __restrict__ row_ptr) {
    const int b = blockIdx.x, t = threadIdx.x;
    int idx0 = b * SCAN_CHUNK + t * 8;
    int loc[8];
    int s = 0;
    #pragma unroll
    for (int i = 0; i < 8; ++i) {
        int idx = idx0 + i;
        loc[i] = (idx < N_NODES) ? deg[idx] : 0;
        s += loc[i];
    }
    __shared__ int tmp[256];
    tmp[t] = s;
    __syncthreads();
    #pragma unroll
    for (int off = 1; off < 256; off <<= 1) {
        int u = (t >= off) ? tmp[t - off] : 0;
        __syncthreads();
        tmp[t] += u;
        __syncthreads();
    }
    int run = tmp[t] - s + bsum[b];
    #pragma unroll
    for (int i = 0; i < 8; ++i) {
        int idx = idx0 + i;
        if (idx < N_NODES) row_ptr[idx] = run;
        run += loc[i];
    }
}

__global__ __launch_bounds__(256) void place_kernel(const int* __restrict__ src,
                                                    const int* __restrict__ dst,
                                                    const float* __restrict__ dis,
                                                    const int* __restrict__ row_ptr,
                                                    int* __restrict__ cursor,
                                                    int* __restrict__ csr_src,
                                                    float* __restrict__ csr_coef) {
    int e = blockIdx.x * 256 + threadIdx.x;
    if (e < E_EDGES) {
        int s = src[e], d = dst[e];
        int pos = row_ptr[d] + atomicAdd(&cursor[d], 1);
        csr_src[pos]  = s;
        csr_coef[pos] = dis[s] * dis[d];
    }
}

// ---------------------------------------------------------------- GEMM
// out[r][c] = sum_k in[r][k] * W[c][k];  64 rows x 64 cols per block, 256 thr.
// LDS XOR-swizzle on float4 granules so inner-loop ds_read_b128 is <=2-way.
// FUSED_MAX: stage relu tile in LDS, segmented max over sorted batch ->
// ~2 atomics per (graph,col) per block instead of per-element atomics.
template<int K, bool FUSED_MAX>
__global__ __launch_bounds__(256) void gemm_k(const float* __restrict__ in,
                                              const float* __restrict__ W,
                                              float* __restrict__ out,
                                              const float* __restrict__ bias,
                                              const int* __restrict__ batch,
                                              int* __restrict__ pooled,
                                              int layer) {
    constexpr int GPR = K / 4;           // float4 granules per row
    __shared__ float smem[64 * K + D * K];
    __shared__ int   bs[64];
    float* Xs = smem;
    float* Ws = smem + 64 * K;
    const int tid = threadIdx.x;
    const size_t row0 = (size_t)blockIdx.x * 64;

    for (int li = tid; li < 64 * GPR; li += 256) {
        int r = li / GPR, g = li % GPR;
        float4 v = *(const float4*)(in + (row0 + r) * K + g * 4);
        int gs = g ^ ((r >> 2) & 7);
        *(float4*)(Xs + r * K + gs * 4) = v;
    }
    for (int li = tid; li < D * GPR; li += 256) {
        int r = li / GPR, g = li % GPR;
        float4 v = *(const float4*)(W + r * K + g * 4);
        int gs = g ^ ((r >> 2) & 7);
        *(float4*)(Ws + r * K + gs * 4) = v;
    }
    if (FUSED_MAX && tid < 64) bs[tid] = batch[row0 + tid];
    __syncthreads();

    const int lane = tid & 63;
    const int wave = tid >> 6;
    const int rg = lane & 15;              // 16 row groups
    const int cg = wave * 4 + (lane >> 4); // 16 col groups
    float acc[4][4] = {};
    #pragma unroll 8
    for (int kq = 0; kq < GPR; ++kq) {
        float4 xv[4], wv[4];
        #pragma unroll
        for (int i = 0; i < 4; ++i)
            xv[i] = *(const float4*)(Xs + (rg * 4 + i) * K + ((kq ^ (rg & 7)) * 4));
        #pragma unroll
        for (int j = 0; j < 4; ++j)
            wv[j] = *(const float4*)(Ws + (cg * 4 + j) * K + ((kq ^ (cg & 7)) * 4));
        #pragma unroll
        for (int i = 0; i < 4; ++i)
            #pragma unroll
            for (int j = 0; j < 4; ++j)
                acc[i][j] += xv[i].x * wv[j].x + xv[i].y * wv[j].y +
                             xv[i].z * wv[j].z + xv[i].w * wv[j].w;
    }

    if constexpr (FUSED_MAX) {
        __syncthreads();                    // done reading Xs/Ws
        float* Ts = smem;                   // 64*68 floats, fits (K=64)
        #pragma unroll
        for (int i = 0; i < 4; ++i) {
            size_t r = row0 + rg * 4 + i;
            float4 o;
            float* op = (float*)&o;
            #pragma unroll
            for (int j = 0; j < 4; ++j)
                op[j] = fmaxf(acc[i][j] + bias[cg * 4 + j], 0.0f);
            *(float4*)(out + r * D + cg * 4) = o;
            *(float4*)(Ts + (rg * 4 + i) * 68 + cg * 4) = o;
        }
        __syncthreads();
        if (tid < 64) {
            const int col = tid;
            float m = Ts[col];
            int bg = bs[0];
            #pragma unroll 8
            for (int r = 1; r < 64; ++r) {
                int b2 = bs[r];            // wave-uniform across cols
                float v = Ts[r * 68 + col];
                if (b2 != bg) {            // uniform branch
                    atomicMax(&pooled[bg * (4 * D) + layer * D + col], __float_as_int(m));
                    bg = b2; m = v;
                } else {
                    m = fmaxf(m, v);
                }
            }
            atomicMax(&pooled[bg * (4 * D) + layer * D + col], __float_as_int(m));
        }
    } else {
        #pragma unroll
        for (int i = 0; i < 4; ++i) {
            size_t r = row0 + rg * 4 + i;
            float4 o = make_float4(acc[i][0], acc[i][1], acc[i][2], acc[i][3]);
            *(float4*)(out + r * D + cg * 4) = o;
        }
    }
}

// ---------------------------------------------------------------- aggregate
// one wave per node, lane = feature. acc = self-loop + bias + sum_{edges}.
__global__ __launch_bounds__(256) void agg_kernel(const int* __restrict__ row_ptr,
                                                  const int* __restrict__ csr_src,
                                                  const float* __restrict__ csr_coef,
                                                  const float* __restrict__ Lbuf,
                                                  const float* __restrict__ dis,
                                                  const float* __restrict__ bias,
                                                  float* __restrict__ A) {
    int v = __builtin_amdgcn_readfirstlane((int)(blockIdx.x * 4) + (int)(threadIdx.x >> 6));
    if (v >= N_NODES) return;
    const int lane = threadIdx.x & 63;
    const int beg = row_ptr[v];
    const int end = row_ptr[v + 1];
    float dd = dis[v];
    float acc = Lbuf[(size_t)v * D + lane] * (dd * dd) + bias[lane];
    #pragma unroll 4
    for (int p = beg; p < end; ++p) {
        int s = csr_src[p];
        float c = csr_coef[p];
        acc += Lbuf[(size_t)s * D + lane] * c;
    }
    A[(size_t)v * D + lane] = acc;
}

// ---------------------------------------------------------------- final MLP
__global__ __launch_bounds__(64) void mlp_kernel(const float* __restrict__ pooled,
                                                 const float* __restrict__ W1,
                                                 const float* __restrict__ b1,
                                                 const float* __restrict__ W2,
                                                 const float* __restrict__ b2,
                                                 float* __restrict__ out) {
    __shared__ float ps[4 * D];
    __shared__ float hs[D];
    const int g = blockIdx.x, t = threadIdx.x;
    *(float4*)(ps + t * 4) = *(const float4*)(pooled + (size_t)g * (4 * D) + t * 4);
    __syncthreads();
    float acc = b1[t];
    const float* w = W1 + (size_t)t * (4 * D);
    #pragma unroll 4
    for (int k = 0; k < 4 * D; k += 4) {
        float4 wv = *(const float4*)(w + k);
        float4 pv = *(const float4*)(ps + k);
        acc += wv.x * pv.x + wv.y * pv.y + wv.z * pv.z + wv.w * pv.w;
    }
    hs[t] = fmaxf(acc, 0.0f);
    __syncthreads();
    if (t < T_OUT) {
        float o = b2[t];
        const float* w2 = W2 + t * D;
        #pragma unroll
        for (int k = 0; k < D; ++k) o += hs[k] * w2[k];
        out[(size_t)g * T_OUT + t] = o;
    }
}

// ---------------------------------------------------------------- launch
extern "C" void kernel_launch(void* const* d_in, const int* in_sizes, int n_in,
                              void* d_out, int out_size, void* d_ws, size_t ws_size,
                              hipStream_t stream) {
    (void)in_sizes; (void)n_in; (void)out_size; (void)ws_size;
    const float* x     = (const float*)d_in[0];
    const int*   ei    = (const int*)d_in[1];
    const int*   batch = (const int*)d_in[2];
    const float* Wc[4] = {(const float*)d_in[4], (const float*)d_in[6],
                          (const float*)d_in[8], (const float*)d_in[10]};
    const float* bc[4] = {(const float*)d_in[5], (const float*)d_in[7],
                          (const float*)d_in[9], (const float*)d_in[11]};
    const float* Wmax = (const float*)d_in[12];
    const float* bmax = (const float*)d_in[13];
    const float* W1   = (const float*)d_in[14];
    const float* b1   = (const float*)d_in[15];
    const float* W2   = (const float*)d_in[16];
    const float* b2   = (const float*)d_in[17];
    float* out = (float*)d_out;

    float* fws = (float*)d_ws;
    size_t off = 0;
    float* L        = fws + off; off += (size_t)N_NODES * D;   // 51.2 MB (ping-pong)
    float* A        = fws + off; off += (size_t)N_NODES * D;   // 51.2 MB
    int*   csr_src  = (int*)(fws + off); off += E_EDGES;       // 12.8 MB
    float* csr_coef = fws + off; off += E_EDGES;               // 12.8 MB
    int*   row_ptr  = (int*)(fws + off); off += N_NODES + 16;
    int*   deg      = (int*)(fws + off); off += N_NODES;
    int*   cursor   = (int*)(fws + off); off += N_NODES;
    float* dis      = fws + off; off += N_NODES;
    int*   pooled   = (int*)(fws + off); off += G_GRAPHS * 4 * D;
    int*   bsum     = (int*)(fws + off); off += SCAN_NBLOCKS + 16;

    const int* srcI = ei;
    const int* dstI = ei + E_EDGES;

    hipMemsetAsync(deg,    0, sizeof(int) * N_NODES, stream);
    hipMemsetAsync(cursor, 0, sizeof(int) * N_NODES, stream);
    hipMemsetAsync(pooled, 0, sizeof(int) * G_GRAPHS * 4 * D, stream);

    deg_kernel <<<(E_EDGES + 255) / 256, 256, 0, stream>>>(dstI, deg);
    dis_kernel <<<(N_NODES + 255) / 256, 256, 0, stream>>>(deg, dis);
    scan_p1<<<SCAN_NBLOCKS, 256, 0, stream>>>(deg, bsum);
    scan_p2<<<1, 128, 0, stream>>>(bsum, row_ptr);
    scan_p3<<<SCAN_NBLOCKS, 256, 0, stream>>>(deg, bsum, row_ptr);
    place_kernel<<<(E_EDGES + 255) / 256, 256, 0, stream>>>(srcI, dstI, dis, row_ptr,
                                                            cursor, csr_src, csr_coef);

    const float* cur = x;
    for (int l = 0; l < 4; ++l) {
        if (l == 0)
            gemm_k<F_IN, false><<<N_NODES / 64, 256, 0, stream>>>(cur, Wc[0], L,
                                                                  nullptr, nullptr, nullptr, 0);
        else
            gemm_k<D, false><<<N_NODES / 64, 256, 0, stream>>>(cur, Wc[l], L,
                                                               nullptr, nullptr, nullptr, 0);
        agg_kernel<<<N_NODES / 4, 256, 0, stream>>>(row_ptr, csr_src, csr_coef,
                                                    L, dis, bc[l], A);
        gemm_k<D, true><<<N_NODES / 64, 256, 0, stream>>>(A, Wmax, L,
                                                          bmax, batch, pooled, l);
        cur = L;
    }
    mlp_kernel<<<G_GRAPHS, 64, 0, stream>>>((const float*)pooled, W1, b1, W2, b2, out);
}

// Round 8
// 1364.669 us; speedup vs baseline: 3.5173x; 1.0668x over previous
//
#include <hip/hip_runtime.h>
#include <hip/hip_bf16.h>
#include <math.h>

constexpr int N_NODES = 200000;
constexpr int E_EDGES = 3200000;
constexpr int F_IN    = 128;
constexpr int D       = 64;
constexpr int G_GRAPHS = 512;
constexpr int T_OUT   = 10;

constexpr int SCAN_CHUNK   = 2048;
constexpr int SCAN_NBLOCKS = (N_NODES + SCAN_CHUNK - 1) / SCAN_CHUNK; // 98

constexpr int PLACE_NPASS = 4;
constexpr int PLACE_RANGE = N_NODES / PLACE_NPASS;   // 50000

// ---------------------------------------------------------------- degree
__global__ __launch_bounds__(256) void deg_kernel(const int* __restrict__ dst,
                                                  int* __restrict__ deg) {
    int e = blockIdx.x * 256 + threadIdx.x;
    if (e < E_EDGES) atomicAdd(&deg[dst[e]], 1);
}

__global__ __launch_bounds__(256) void dis_kernel(const int* __restrict__ deg,
                                                  float* __restrict__ dis) {
    int i = blockIdx.x * 256 + threadIdx.x;
    if (i < N_NODES) dis[i] = 1.0f / sqrtf((float)deg[i] + 1.0f);
}

// ----------------------------------------------------- 3-phase parallel scan
__global__ __launch_bounds__(256) void scan_p1(const int* __restrict__ deg,
                                               int* __restrict__ bsum) {
    const int b = blockIdx.x, t = threadIdx.x;
    int idx0 = b * SCAN_CHUNK + t * 8;
    int s = 0;
    #pragma unroll
    for (int i = 0; i < 8; ++i) {
        int idx = idx0 + i;
        if (idx < N_NODES) s += deg[idx];
    }
    #pragma unroll
    for (int off = 32; off; off >>= 1) s += __shfl_down(s, off, 64);
    __shared__ int ws[4];
    if ((t & 63) == 0) ws[t >> 6] = s;
    __syncthreads();
    if (t == 0) bsum[b] = ws[0] + ws[1] + ws[2] + ws[3];
}

__global__ __launch_bounds__(128) void scan_p2(int* __restrict__ bsum,
                                               int* __restrict__ row_ptr) {
    __shared__ int tmp[128];
    const int t = threadIdx.x;
    int v = (t < SCAN_NBLOCKS) ? bsum[t] : 0;
    tmp[t] = v;
    __syncthreads();
    #pragma unroll
    for (int off = 1; off < 128; off <<= 1) {
        int u = (t >= off) ? tmp[t - off] : 0;
        __syncthreads();
        tmp[t] += u;
        __syncthreads();
    }
    if (t < SCAN_NBLOCKS) bsum[t] = tmp[t] - v;   // exclusive
    if (t == 0) row_ptr[N_NODES] = E_EDGES;
}

__global__ __launch_bounds__(256) void scan_p3(const int* __restrict__ deg,
                                               const int* __restrict__ bsum,
                                               int* __restrict__ row_ptr) {
    const int b = blockIdx.x, t = threadIdx.x;
    int idx0 = b * SCAN_CHUNK + t * 8;
    int loc[8];
    int s = 0;
    #pragma unroll
    for (int i = 0; i < 8; ++i) {
        int idx = idx0 + i;
        loc[i] = (idx < N_NODES) ? deg[idx] : 0;
        s += loc[i];
    }
    __shared__ int tmp[256];
    tmp[t] = s;
    __syncthreads();
    #pragma unroll
    for (int off = 1; off < 256; off <<= 1) {
        int u = (t >= off) ? tmp[t - off] : 0;
        __syncthreads();
        tmp[t] += u;
        __syncthreads();
    }
    int run = tmp[t] - s + bsum[b];
    #pragma unroll
    for (int i = 0; i < 8; ++i) {
        int idx = idx0 + i;
        if (idx < N_NODES) row_ptr[idx] = run;
        run += loc[i];
    }
}

// ------------------------------------------------ placement (range-filtered)
// One pass per dst-range so the active CSR write window (~3.2 MB) stays
// L2-resident and cache lines fill before writeback. csr stores src only;
// the sym-norm coefficient is folded into the GEMM epilogue (h' = h*dis).
__global__ __launch_bounds__(256) void place_pass(const int* __restrict__ src,
                                                  const int* __restrict__ dst,
                                                  const int* __restrict__ row_ptr,
                                                  int* __restrict__ cursor,
                                                  int* __restrict__ csr_src,
                                                  int lo, int hi) {
    int e0 = (blockIdx.x * 256 + threadIdx.x) * 4;
    if (e0 >= E_EDGES) return;
    int4 d4 = *(const int4*)(dst + e0);
    const int* dp = (const int*)&d4;
    #pragma unroll
    for (int i = 0; i < 4; ++i) {
        int d = dp[i];
        if (d >= lo && d < hi) {
            int pos = row_ptr[d] + atomicAdd(&cursor[d], 1);
            csr_src[pos] = src[e0 + i];
        }
    }
}

// ---------------------------------------------------------------- GEMM
// out[r][c] = sum_k in[r][k] * W[c][k];  64 rows x 64 cols per block, 256 thr.
// LDS XOR-swizzle on float4 granules so inner-loop ds_read_b128 is <=2-way.
// SCALE: multiply output row r by dis[r] (folds GCN sym-norm src coefficient).
// FUSED_MAX: relu + segmented max-pool over sorted batch via LDS tile.
template<int K, bool FUSED_MAX, bool SCALE>
__global__ __launch_bounds__(256) void gemm_k(const float* __restrict__ in,
                                              const float* __restrict__ W,
                                              float* __restrict__ out,
                                              const float* __restrict__ bias,
                                              const int* __restrict__ batch,
                                              int* __restrict__ pooled,
                                              const float* __restrict__ dis,
                                              int layer) {
    constexpr int GPR = K / 4;           // float4 granules per row
    __shared__ float smem[64 * K + D * K];
    __shared__ int   bs[64];
    __shared__ float ds[64];
    float* Xs = smem;
    float* Ws = smem + 64 * K;
    const int tid = threadIdx.x;
    const size_t row0 = (size_t)blockIdx.x * 64;

    for (int li = tid; li < 64 * GPR; li += 256) {
        int r = li / GPR, g = li % GPR;
        float4 v = *(const float4*)(in + (row0 + r) * K + g * 4);
        int gs = g ^ ((r >> 2) & 7);
        *(float4*)(Xs + r * K + gs * 4) = v;
    }
    for (int li = tid; li < D * GPR; li += 256) {
        int r = li / GPR, g = li % GPR;
        float4 v = *(const float4*)(W + r * K + g * 4);
        int gs = g ^ ((r >> 2) & 7);
        *(float4*)(Ws + r * K + gs * 4) = v;
    }
    if (FUSED_MAX && tid < 64) bs[tid] = batch[row0 + tid];
    if (SCALE && tid < 64)     ds[tid] = dis[row0 + tid];
    __syncthreads();

    const int lane = tid & 63;
    const int wave = tid >> 6;
    const int rg = lane & 15;              // 16 row groups
    const int cg = wave * 4 + (lane >> 4); // 16 col groups
    float acc[4][4] = {};
    #pragma unroll 8
    for (int kq = 0; kq < GPR; ++kq) {
        float4 xv[4], wv[4];
        #pragma unroll
        for (int i = 0; i < 4; ++i)
            xv[i] = *(const float4*)(Xs + (rg * 4 + i) * K + ((kq ^ (rg & 7)) * 4));
        #pragma unroll
        for (int j = 0; j < 4; ++j)
            wv[j] = *(const float4*)(Ws + (cg * 4 + j) * K + ((kq ^ (cg & 7)) * 4));
        #pragma unroll
        for (int i = 0; i < 4; ++i)
            #pragma unroll
            for (int j = 0; j < 4; ++j)
                acc[i][j] += xv[i].x * wv[j].x + xv[i].y * wv[j].y +
                             xv[i].z * wv[j].z + xv[i].w * wv[j].w;
    }

    if constexpr (FUSED_MAX) {
        __syncthreads();                    // done reading Xs/Ws
        float* Ts = smem;                   // 64*68 floats, fits (K=64)
        #pragma unroll
        for (int i = 0; i < 4; ++i) {
            size_t r = row0 + rg * 4 + i;
            float4 o;
            float* op = (float*)&o;
            #pragma unroll
            for (int j = 0; j < 4; ++j)
                op[j] = fmaxf(acc[i][j] + bias[cg * 4 + j], 0.0f);
            *(float4*)(out + r * D + cg * 4) = o;
            *(float4*)(Ts + (rg * 4 + i) * 68 + cg * 4) = o;
        }
        __syncthreads();
        if (tid < 64) {
            const int col = tid;
            float m = Ts[col];
            int bg = bs[0];
            #pragma unroll 8
            for (int r = 1; r < 64; ++r) {
                int b2 = bs[r];            // wave-uniform across cols
                float v = Ts[r * 68 + col];
                if (b2 != bg) {            // uniform branch
                    atomicMax(&pooled[bg * (4 * D) + layer * D + col], __float_as_int(m));
                    bg = b2; m = v;
                } else {
                    m = fmaxf(m, v);
                }
            }
            atomicMax(&pooled[bg * (4 * D) + layer * D + col], __float_as_int(m));
        }
    } else {
        #pragma unroll
        for (int i = 0; i < 4; ++i) {
            size_t r = row0 + rg * 4 + i;
            float sc = SCALE ? ds[rg * 4 + i] : 1.0f;
            float4 o = make_float4(acc[i][0] * sc, acc[i][1] * sc,
                                   acc[i][2] * sc, acc[i][3] * sc);
            *(float4*)(out + r * D + cg * 4) = o;
        }
    }
}

// ---------------------------------------------------------------- aggregate
// one wave per node, lane = feature. Input rows are pre-scaled by dis[src]:
// A[v] = dis[v] * (h'[v] + sum_edges h'[s]) + bias.
__global__ __launch_bounds__(256) void agg_kernel(const int* __restrict__ row_ptr,
                                                  const int* __restrict__ csr_src,
                                                  const float* __restrict__ Lbuf,
                                                  const float* __restrict__ dis,
                                                  const float* __restrict__ bias,
                                                  float* __restrict__ A) {
    int v = __builtin_amdgcn_readfirstlane((int)(blockIdx.x * 4) + (int)(threadIdx.x >> 6));
    if (v >= N_NODES) return;
    const int lane = threadIdx.x & 63;
    const int beg = row_ptr[v];
    const int end = row_ptr[v + 1];
    float acc = Lbuf[(size_t)v * D + lane];
    #pragma unroll 4
    for (int p = beg; p < end; ++p) {
        int s = csr_src[p];
        acc += Lbuf[(size_t)s * D + lane];
    }
    A[(size_t)v * D + lane] = acc * dis[v] + bias[lane];
}

// ---------------------------------------------------------------- final MLP
__global__ __launch_bounds__(64) void mlp_kernel(const float* __restrict__ pooled,
                                                 const float* __restrict__ W1,
                                                 const float* __restrict__ b1,
                                                 const float* __restrict__ W2,
                                                 const float* __restrict__ b2,
                                                 float* __restrict__ out) {
    __shared__ float ps[4 * D];
    __shared__ float hs[D];
    const int g = blockIdx.x, t = threadIdx.x;
    *(float4*)(ps + t * 4) = *(const float4*)(pooled + (size_t)g * (4 * D) + t * 4);
    __syncthreads();
    float acc = b1[t];
    const float* w = W1 + (size_t)t * (4 * D);
    #pragma unroll 4
    for (int k = 0; k < 4 * D; k += 4) {
        float4 wv = *(const float4*)(w + k);
        float4 pv = *(const float4*)(ps + k);
        acc += wv.x * pv.x + wv.y * pv.y + wv.z * pv.z + wv.w * pv.w;
    }
    hs[t] = fmaxf(acc, 0.0f);
    __syncthreads();
    if (t < T_OUT) {
        float o = b2[t];
        const float* w2 = W2 + t * D;
        #pragma unroll
        for (int k = 0; k < D; ++k) o += hs[k] * w2[k];
        out[(size_t)g * T_OUT + t] = o;
    }
}

// ---------------------------------------------------------------- launch
extern "C" void kernel_launch(void* const* d_in, const int* in_sizes, int n_in,
                              void* d_out, int out_size, void* d_ws, size_t ws_size,
                              hipStream_t stream) {
    (void)in_sizes; (void)n_in; (void)out_size; (void)ws_size;
    const float* x     = (const float*)d_in[0];
    const int*   ei    = (const int*)d_in[1];
    const int*   batch = (const int*)d_in[2];
    const float* Wc[4] = {(const float*)d_in[4], (const float*)d_in[6],
                          (const float*)d_in[8], (const float*)d_in[10]};
    const float* bc[4] = {(const float*)d_in[5], (const float*)d_in[7],
                          (const float*)d_in[9], (const float*)d_in[11]};
    const float* Wmax = (const float*)d_in[12];
    const float* bmax = (const float*)d_in[13];
    const float* W1   = (const float*)d_in[14];
    const float* b1   = (const float*)d_in[15];
    const float* W2   = (const float*)d_in[16];
    const float* b2   = (const float*)d_in[17];
    float* out = (float*)d_out;

    float* fws = (float*)d_ws;
    size_t off = 0;
    float* L        = fws + off; off += (size_t)N_NODES * D;   // 51.2 MB (ping-pong)
    float* A        = fws + off; off += (size_t)N_NODES * D;   // 51.2 MB
    int*   csr_src  = (int*)(fws + off); off += E_EDGES;       // 12.8 MB
    int*   row_ptr  = (int*)(fws + off); off += N_NODES + 16;
    int*   deg      = (int*)(fws + off); off += N_NODES;
    int*   cursor   = (int*)(fws + off); off += N_NODES;
    float* dis      = fws + off; off += N_NODES;
    int*   pooled   = (int*)(fws + off); off += G_GRAPHS * 4 * D;
    int*   bsum     = (int*)(fws + off); off += SCAN_NBLOCKS + 16;

    const int* srcI = ei;
    const int* dstI = ei + E_EDGES;

    hipMemsetAsync(deg,    0, sizeof(int) * N_NODES, stream);
    hipMemsetAsync(cursor, 0, sizeof(int) * N_NODES, stream);
    hipMemsetAsync(pooled, 0, sizeof(int) * G_GRAPHS * 4 * D, stream);

    deg_kernel <<<(E_EDGES + 255) / 256, 256, 0, stream>>>(dstI, deg);
    dis_kernel <<<(N_NODES + 255) / 256, 256, 0, stream>>>(deg, dis);
    scan_p1<<<SCAN_NBLOCKS, 256, 0, stream>>>(deg, bsum);
    scan_p2<<<1, 128, 0, stream>>>(bsum, row_ptr);
    scan_p3<<<SCAN_NBLOCKS, 256, 0, stream>>>(deg, bsum, row_ptr);
    for (int p = 0; p < PLACE_NPASS; ++p)
        place_pass<<<E_EDGES / (256 * 4), 256, 0, stream>>>(srcI, dstI, row_ptr,
                                                            cursor, csr_src,
                                                            p * PLACE_RANGE,
                                                            (p + 1) * PLACE_RANGE);

    const float* cur = x;
    for (int l = 0; l < 4; ++l) {
        if (l == 0)
            gemm_k<F_IN, false, true><<<N_NODES / 64, 256, 0, stream>>>(
                cur, Wc[0], L, nullptr, nullptr, nullptr, dis, 0);
        else
            gemm_k<D, false, true><<<N_NODES / 64, 256, 0, stream>>>(
                cur, Wc[l], L, nullptr, nullptr, nullptr, dis, 0);
        agg_kernel<<<N_NODES / 4, 256, 0, stream>>>(row_ptr, csr_src,
                                                    L, dis, bc[l], A);
        gemm_k<D, true, false><<<N_NODES / 64, 256, 0, stream>>>(
            A, Wmax, L, bmax, batch, pooled, nullptr, l);
        cur = L;
    }
    mlp_kernel<<<G_GRAPHS, 64, 0, stream>>>((const float*)pooled, W1, b1, W2, b2, out);
}

// Round 12
// 1363.500 us; speedup vs baseline: 3.5203x; 1.0009x over previous
//
#include <hip/hip_runtime.h>
#include <hip/hip_bf16.h>
#include <math.h>

constexpr int N_NODES = 200000;
constexpr int E_EDGES = 3200000;
constexpr int F_IN    = 128;
constexpr int D       = 64;
constexpr int G_GRAPHS = 512;
constexpr int T_OUT   = 10;

constexpr int SCAN_CHUNK   = 2048;
constexpr int SCAN_NBLOCKS = (N_NODES + SCAN_CHUNK - 1) / SCAN_CHUNK; // 98

constexpr int NPASS = 4;
constexpr int PASS_RANGE = N_NODES / NPASS;   // 50000

// ------------------------------------------------ degree (range-filtered)
// Same L2-residency trick as place_pass: each pass only touches a 200 KB
// histogram window so the atomic RMW lines stay cached instead of
// write-through scattering to HBM (deg_kernel showed 100 MB WRITE_SIZE).
__global__ __launch_bounds__(256) void deg_pass(const int* __restrict__ dst,
                                                int* __restrict__ deg,
                                                int lo, int hi) {
    int e0 = (blockIdx.x * 256 + threadIdx.x) * 4;
    if (e0 >= E_EDGES) return;
    int4 d4 = *(const int4*)(dst + e0);
    const int* dp = (const int*)&d4;
    #pragma unroll
    for (int i = 0; i < 4; ++i) {
        int d = dp[i];
        if (d >= lo && d < hi) atomicAdd(&deg[d], 1);
    }
}

__global__ __launch_bounds__(256) void dis_kernel(const int* __restrict__ deg,
                                                  float* __restrict__ dis) {
    int i = blockIdx.x * 256 + threadIdx.x;
    if (i < N_NODES) dis[i] = 1.0f / sqrtf((float)deg[i] + 1.0f);
}

// ----------------------------------------------------- 3-phase parallel scan
__global__ __launch_bounds__(256) void scan_p1(const int* __restrict__ deg,
                                               int* __restrict__ bsum) {
    const int b = blockIdx.x, t = threadIdx.x;
    int idx0 = b * SCAN_CHUNK + t * 8;
    int s = 0;
    #pragma unroll
    for (int i = 0; i < 8; ++i) {
        int idx = idx0 + i;
        if (idx < N_NODES) s += deg[idx];
    }
    #pragma unroll
    for (int off = 32; off; off >>= 1) s += __shfl_down(s, off, 64);
    __shared__ int ws[4];
    if ((t & 63) == 0) ws[t >> 6] = s;
    __syncthreads();
    if (t == 0) bsum[b] = ws[0] + ws[1] + ws[2] + ws[3];
}

__global__ __launch_bounds__(128) void scan_p2(int* __restrict__ bsum,
                                               int* __restrict__ row_ptr) {
    __shared__ int tmp[128];
    const int t = threadIdx.x;
    int v = (t < SCAN_NBLOCKS) ? bsum[t] : 0;
    tmp[t] = v;
    __syncthreads();
    #pragma unroll
    for (int off = 1; off < 128; off <<= 1) {
        int u = (t >= off) ? tmp[t - off] : 0;
        __syncthreads();
        tmp[t] += u;
        __syncthreads();
    }
    if (t < SCAN_NBLOCKS) bsum[t] = tmp[t] - v;   // exclusive
    if (t == 0) row_ptr[N_NODES] = E_EDGES;
}

__global__ __launch_bounds__(256) void scan_p3(const int* __restrict__ deg,
                                               const int* __restrict__ bsum,
                                               int* __restrict__ row_ptr) {
    const int b = blockIdx.x, t = threadIdx.x;
    int idx0 = b * SCAN_CHUNK + t * 8;
    int loc[8];
    int s = 0;
    #pragma unroll
    for (int i = 0; i < 8; ++i) {
        int idx = idx0 + i;
        loc[i] = (idx < N_NODES) ? deg[idx] : 0;
        s += loc[i];
    }
    __shared__ int tmp[256];
    tmp[t] = s;
    __syncthreads();
    #pragma unroll
    for (int off = 1; off < 256; off <<= 1) {
        int u = (t >= off) ? tmp[t - off] : 0;
        __syncthreads();
        tmp[t] += u;
        __syncthreads();
    }
    int run = tmp[t] - s + bsum[b];
    #pragma unroll
    for (int i = 0; i < 8; ++i) {
        int idx = idx0 + i;
        if (idx < N_NODES) row_ptr[idx] = run;
        run += loc[i];
    }
}

// ------------------------------------------------ placement (range-filtered)
__global__ __launch_bounds__(256) void place_pass(const int* __restrict__ src,
                                                  const int* __restrict__ dst,
                                                  const int* __restrict__ row_ptr,
                                                  int* __restrict__ cursor,
                                                  int* __restrict__ csr_src,
                                                  int lo, int hi) {
    int e0 = (blockIdx.x * 256 + threadIdx.x) * 4;
    if (e0 >= E_EDGES) return;
    int4 d4 = *(const int4*)(dst + e0);
    const int* dp = (const int*)&d4;
    #pragma unroll
    for (int i = 0; i < 4; ++i) {
        int d = dp[i];
        if (d >= lo && d < hi) {
            int pos = row_ptr[d] + atomicAdd(&cursor[d], 1);
            csr_src[pos] = src[e0 + i];
        }
    }
}

// ------------------------------------------- combined bias b' = Wmax@bc + bmax
__global__ __launch_bounds__(256) void bprime_kernel(const float* __restrict__ Wmax,
                                                     const float* __restrict__ bmax,
                                                     const float* __restrict__ bc0,
                                                     const float* __restrict__ bc1,
                                                     const float* __restrict__ bc2,
                                                     const float* __restrict__ bc3,
                                                     float* __restrict__ bprime) {
    const int l = threadIdx.x >> 6, c = threadIdx.x & 63;
    const float* bc = (l == 0) ? bc0 : (l == 1) ? bc1 : (l == 2) ? bc2 : bc3;
    float s = bmax[c];
    const float* w = Wmax + c * D;
    #pragma unroll
    for (int k = 0; k < D; k += 4) {
        float4 wv = *(const float4*)(w + k);
        float4 bv = *(const float4*)(bc + k);
        s += wv.x * bv.x + wv.y * bv.y + wv.z * bv.z + wv.w * bv.w;
    }
    bprime[l * D + c] = s;
}

// ---------------------------------------------------------------- GEMM (layer0)
// out[r][c] = dis[r] * sum_k in[r][k] * W[c][k];  64x64 per block, 256 thr.
template<int K>
__global__ __launch_bounds__(256) void gemm_k(const float* __restrict__ in,
                                              const float* __restrict__ W,
                                              float* __restrict__ out,
                                              const float* __restrict__ dis) {
    constexpr int GPR = K / 4;
    __shared__ float Xs[64 * K];
    __shared__ float Ws[D * K];
    __shared__ float ds[64];
    const int tid = threadIdx.x;
    const size_t row0 = (size_t)blockIdx.x * 64;

    for (int li = tid; li < 64 * GPR; li += 256) {
        int r = li / GPR, g = li % GPR;
        float4 v = *(const float4*)(in + (row0 + r) * K + g * 4);
        int gs = g ^ ((r >> 2) & 7);
        *(float4*)(Xs + r * K + gs * 4) = v;
    }
    for (int li = tid; li < D * GPR; li += 256) {
        int r = li / GPR, g = li % GPR;
        float4 v = *(const float4*)(W + r * K + g * 4);
        int gs = g ^ ((r >> 2) & 7);
        *(float4*)(Ws + r * K + gs * 4) = v;
    }
    if (tid < 64) ds[tid] = dis[row0 + tid];
    __syncthreads();

    const int lane = tid & 63;
    const int wave = tid >> 6;
    const int rg = lane & 15;
    const int cg = wave * 4 + (lane >> 4);
    float acc[4][4] = {};
    #pragma unroll 8
    for (int kq = 0; kq < GPR; ++kq) {
        float4 xv[4], wv[4];
        #pragma unroll
        for (int i = 0; i < 4; ++i)
            xv[i] = *(const float4*)(Xs + (rg * 4 + i) * K + ((kq ^ (rg & 7)) * 4));
        #pragma unroll
        for (int j = 0; j < 4; ++j)
            wv[j] = *(const float4*)(Ws + (cg * 4 + j) * K + ((kq ^ (cg & 7)) * 4));
        #pragma unroll
        for (int i = 0; i < 4; ++i)
            #pragma unroll
            for (int j = 0; j < 4; ++j)
                acc[i][j] += xv[i].x * wv[j].x + xv[i].y * wv[j].y +
                             xv[i].z * wv[j].z + xv[i].w * wv[j].w;
    }
    #pragma unroll
    for (int i = 0; i < 4; ++i) {
        size_t r = row0 + rg * 4 + i;
        float sc = ds[rg * 4 + i];
        float4 o = make_float4(acc[i][0] * sc, acc[i][1] * sc,
                               acc[i][2] * sc, acc[i][3] * sc);
        *(float4*)(out + r * D + cg * 4) = o;
    }
}

// ------------------------------------------------------- fused double-GEMM
// T = relu(A @ Wmax^T + b')  [kept in LDS only]
//   -> segmented max-pool into pooled[graph][layer*D + col]
//   -> H = (T @ Wcn^T) * dis[r]   (next layer's pre-scaled conv input)
template<bool HAS_NEXT>
__global__ __launch_bounds__(256) void fused2_kernel(const float* __restrict__ A,
                                                     const float* __restrict__ Wmax,
                                                     const float* __restrict__ Wcn,
                                                     const float* __restrict__ bprime,
                                                     const int* __restrict__ batch,
                                                     const float* __restrict__ dis,
                                                     int* __restrict__ pooled,
                                                     float* __restrict__ Hout,
                                                     int layer) {
    __shared__ float Xs[64 * D];   // A tile, then T tile (same swizzled layout)
    __shared__ float Ws[64 * D];   // Wmax
    __shared__ float Ws2[64 * D];  // Wc_next
    __shared__ int   bs[64];
    __shared__ float ds[64];
    __shared__ float bb[64];
    const int tid = threadIdx.x;
    const size_t row0 = (size_t)blockIdx.x * 64;

    for (int li = tid; li < 64 * 16; li += 256) {
        int r = li >> 4, g = li & 15;
        float4 v = *(const float4*)(A + (row0 + r) * D + g * 4);
        *(float4*)(Xs + r * D + ((g ^ ((r >> 2) & 7)) * 4)) = v;
    }
    for (int li = tid; li < 64 * 16; li += 256) {
        int r = li >> 4, g = li & 15;
        float4 v = *(const float4*)(Wmax + r * D + g * 4);
        *(float4*)(Ws + r * D + ((g ^ ((r >> 2) & 7)) * 4)) = v;
    }
    if (HAS_NEXT)
        for (int li = tid; li < 64 * 16; li += 256) {
            int r = li >> 4, g = li & 15;
            float4 v = *(const float4*)(Wcn + r * D + g * 4);
            *(float4*)(Ws2 + r * D + ((g ^ ((r >> 2) & 7)) * 4)) = v;
        }
    if (tid < 64) {
        bs[tid] = batch[row0 + tid];
        bb[tid] = bprime[tid];
        if (HAS_NEXT) ds[tid] = dis[row0 + tid];
    }
    __syncthreads();

    const int lane = tid & 63;
    const int wave = tid >> 6;
    const int rg = lane & 15;
    const int cg = wave * 4 + (lane >> 4);

    // phase 2: acc = A @ Wmax^T
    float acc[4][4] = {};
    #pragma unroll 8
    for (int kq = 0; kq < 16; ++kq) {
        float4 xv[4], wv[4];
        #pragma unroll
        for (int i = 0; i < 4; ++i)
            xv[i] = *(const float4*)(Xs + (rg * 4 + i) * D + ((kq ^ (rg & 7)) * 4));
        #pragma unroll
        for (int j = 0; j < 4; ++j)
            wv[j] = *(const float4*)(Ws + (cg * 4 + j) * D + ((kq ^ (cg & 7)) * 4));
        #pragma unroll
        for (int i = 0; i < 4; ++i)
            #pragma unroll
            for (int j = 0; j < 4; ++j)
                acc[i][j] += xv[i].x * wv[j].x + xv[i].y * wv[j].y +
                             xv[i].z * wv[j].z + xv[i].w * wv[j].w;
    }

    // phase 3: T = relu(acc + b') -> back into Xs (same swizzled layout)
    __syncthreads();                 // all phase-2 reads of Xs complete
    #pragma unroll
    for (int i = 0; i < 4; ++i) {
        float4 o;
        float* op = (float*)&o;
        #pragma unroll
        for (int j = 0; j < 4; ++j)
            op[j] = fmaxf(acc[i][j] + bb[cg * 4 + j], 0.0f);
        *(float4*)(Xs + (rg * 4 + i) * D + ((cg ^ (rg & 7)) * 4)) = o;
    }
    __syncthreads();

    // pooling: wave 0, one column per thread, segmented over sorted batch
    if (tid < 64) {
        const int col = tid;
        const int cgr = col >> 2, ce = col & 3;
        float m = Xs[(cgr ^ 0) * 4 + ce];   // row 0: (r>>2)&7 == 0
        int bg = bs[0];
        #pragma unroll 8
        for (int r = 1; r < 64; ++r) {
            int b2 = bs[r];
            float v = Xs[r * D + ((cgr ^ ((r >> 2) & 7)) * 4) + ce];
            if (b2 != bg) {
                atomicMax(&pooled[bg * (4 * D) + layer * D + col], __float_as_int(m));
                bg = b2; m = v;
            } else {
                m = fmaxf(m, v);
            }
        }
        atomicMax(&pooled[bg * (4 * D) + layer * D + col], __float_as_int(m));
    }

    // phase 4: H = (T @ Wcn^T) * dis
    if (HAS_NEXT) {
        float acc2[4][4] = {};
        #pragma unroll 8
        for (int kq = 0; kq < 16; ++kq) {
            float4 xv[4], wv[4];
            #pragma unroll
            for (int i = 0; i < 4; ++i)
                xv[i] = *(const float4*)(Xs + (rg * 4 + i) * D + ((kq ^ (rg & 7)) * 4));
            #pragma unroll
            for (int j = 0; j < 4; ++j)
                wv[j] = *(const float4*)(Ws2 + (cg * 4 + j) * D + ((kq ^ (cg & 7)) * 4));
            #pragma unroll
            for (int i = 0; i < 4; ++i)
                #pragma unroll
                for (int j = 0; j < 4; ++j)
                    acc2[i][j] += xv[i].x * wv[j].x + xv[i].y * wv[j].y +
                                  xv[i].z * wv[j].z + xv[i].w * wv[j].w;
        }
        #pragma unroll
        for (int i = 0; i < 4; ++i) {
            size_t r = row0 + rg * 4 + i;
            float sc = ds[rg * 4 + i];
            float4 o = make_float4(acc2[i][0] * sc, acc2[i][1] * sc,
                                   acc2[i][2] * sc, acc2[i][3] * sc);
            *(float4*)(Hout + r * D + cg * 4) = o;
        }
    }
}

// ---------------------------------------------------------------- aggregate
// A[v] = dis[v] * (h'[v] + sum_edges h'[s])   (h' pre-scaled by dis; no bias)
__global__ __launch_bounds__(256) void agg_kernel(const int* __restrict__ row_ptr,
                                                  const int* __restrict__ csr_src,
                                                  const float* __restrict__ Lbuf,
                                                  const float* __restrict__ dis,
                                                  float* __restrict__ A) {
    int v = __builtin_amdgcn_readfirstlane((int)(blockIdx.x * 4) + (int)(threadIdx.x >> 6));
    if (v >= N_NODES) return;
    const int lane = threadIdx.x & 63;
    const int beg = row_ptr[v];
    const int end = row_ptr[v + 1];
    float acc = Lbuf[(size_t)v * D + lane];
    #pragma unroll 4
    for (int p = beg; p < end; ++p) {
        int s = csr_src[p];
        acc += Lbuf[(size_t)s * D + lane];
    }
    A[(size_t)v * D + lane] = acc * dis[v];
}

// ---------------------------------------------------------------- final MLP
__global__ __launch_bounds__(64) void mlp_kernel(const float* __restrict__ pooled,
                                                 const float* __restrict__ W1,
                                                 const float* __restrict__ b1,
                                                 const float* __restrict__ W2,
                                                 const float* __restrict__ b2,
                                                 float* __restrict__ out) {
    __shared__ float ps[4 * D];
    __shared__ float hs[D];
    const int g = blockIdx.x, t = threadIdx.x;
    *(float4*)(ps + t * 4) = *(const float4*)(pooled + (size_t)g * (4 * D) + t * 4);
    __syncthreads();
    float acc = b1[t];
    const float* w = W1 + (size_t)t * (4 * D);
    #pragma unroll 4
    for (int k = 0; k < 4 * D; k += 4) {
        float4 wv = *(const float4*)(w + k);
        float4 pv = *(const float4*)(ps + k);
        acc += wv.x * pv.x + wv.y * pv.y + wv.z * pv.z + wv.w * pv.w;
    }
    hs[t] = fmaxf(acc, 0.0f);
    __syncthreads();
    if (t < T_OUT) {
        float o = b2[t];
        const float* w2 = W2 + t * D;
        #pragma unroll
        for (int k = 0; k < D; ++k) o += hs[k] * w2[k];
        out[(size_t)g * T_OUT + t] = o;
    }
}

// ---------------------------------------------------------------- launch
extern "C" void kernel_launch(void* const* d_in, const int* in_sizes, int n_in,
                              void* d_out, int out_size, void* d_ws, size_t ws_size,
                              hipStream_t stream) {
    (void)in_sizes; (void)n_in; (void)out_size; (void)ws_size;
    const float* x     = (const float*)d_in[0];
    const int*   ei    = (const int*)d_in[1];
    const int*   batch = (const int*)d_in[2];
    const float* Wc[4] = {(const float*)d_in[4], (const float*)d_in[6],
                          (const float*)d_in[8], (const float*)d_in[10]};
    const float* bc[4] = {(const float*)d_in[5], (const float*)d_in[7],
                          (const float*)d_in[9], (const float*)d_in[11]};
    const float* Wmax = (const float*)d_in[12];
    const float* bmax = (const float*)d_in[13];
    const float* W1   = (const float*)d_in[14];
    const float* b1   = (const float*)d_in[15];
    const float* W2   = (const float*)d_in[16];
    const float* b2   = (const float*)d_in[17];
    float* out = (float*)d_out;

    float* fws = (float*)d_ws;
    size_t off = 0;
    float* L        = fws + off; off += (size_t)N_NODES * D;   // h' buffer
    float* A        = fws + off; off += (size_t)N_NODES * D;   // agg buffer
    int*   csr_src  = (int*)(fws + off); off += E_EDGES;
    int*   row_ptr  = (int*)(fws + off); off += N_NODES + 16;
    int*   deg      = (int*)(fws + off); off += N_NODES;
    int*   cursor   = (int*)(fws + off); off += N_NODES;
    float* dis      = fws + off; off += N_NODES;
    int*   pooled   = (int*)(fws + off); off += G_GRAPHS * 4 * D;
    int*   bsum     = (int*)(fws + off); off += SCAN_NBLOCKS + 16;
    float* bprime   = fws + off; off += 4 * D;

    const int* srcI = ei;
    const int* dstI = ei + E_EDGES;

    hipMemsetAsync(deg,    0, sizeof(int) * N_NODES, stream);
    hipMemsetAsync(cursor, 0, sizeof(int) * N_NODES, stream);
    hipMemsetAsync(pooled, 0, sizeof(int) * G_GRAPHS * 4 * D, stream);

    for (int p = 0; p < NPASS; ++p)
        deg_pass<<<E_EDGES / (256 * 4), 256, 0, stream>>>(dstI, deg,
                                                          p * PASS_RANGE,
                                                          (p + 1) * PASS_RANGE);
    dis_kernel<<<(N_NODES + 255) / 256, 256, 0, stream>>>(deg, dis);
    scan_p1<<<SCAN_NBLOCKS, 256, 0, stream>>>(deg, bsum);
    scan_p2<<<1, 128, 0, stream>>>(bsum, row_ptr);
    scan_p3<<<SCAN_NBLOCKS, 256, 0, stream>>>(deg, bsum, row_ptr);
    for (int p = 0; p < NPASS; ++p)
        place_pass<<<E_EDGES / (256 * 4), 256, 0, stream>>>(srcI, dstI, row_ptr,
                                                            cursor, csr_src,
                                                            p * PASS_RANGE,
                                                            (p + 1) * PASS_RANGE);
    bprime_kernel<<<1, 256, 0, stream>>>(Wmax, bmax, bc[0], bc[1], bc[2], bc[3],
                                         bprime);

    // layer 0 conv GEMM: L = (x @ Wc0^T) * dis
    gemm_k<F_IN><<<N_NODES / 64, 256, 0, stream>>>(x, Wc[0], L, dis);

    for (int l = 0; l < 4; ++l) {
        agg_kernel<<<N_NODES / 4, 256, 0, stream>>>(row_ptr, csr_src, L, dis, A);
        if (l < 3)
            fused2_kernel<true><<<N_NODES / 64, 256, 0, stream>>>(
                A, Wmax, Wc[l + 1], bprime + l * D, batch, dis, pooled, L, l);
        else
            fused2_kernel<false><<<N_NODES / 64, 256, 0, stream>>>(
                A, Wmax, nullptr, bprime + l * D, batch, nullptr, pooled, nullptr, l);
    }
    mlp_kernel<<<G_GRAPHS, 64, 0, stream>>>((const float*)pooled, W1, b1, W2, b2, out);
}